// Round 1
// baseline (7397.836 us; speedup 1.0000x reference)
//
#include <hip/hip_runtime.h>
#include <math.h>

// ---------------- problem constants ----------------
#define NBAR   39
#define NPOPS  8
#define PSZ    32
#define TSTEPS 64
#define BATCH  64
#define CCH    64              // compressed channels
#define NEUR   (NBAR*PSZ)      // 1248
#define NCONNS 37
#define TCH    16              // time chunk (4 chunks of 16)

// connectivity: SRC[i] = rows j with ALLTOALL[j][i] != 0
constexpr int C_NSRC[NPOPS] = {5,5,6,6,4,3,6,2};
constexpr int C_OFF [NPOPS] = {0,5,10,16,22,26,29,35};
constexpr int C_SRCS[NCONNS] = {0,1,2,3,4, 0,1,2,3,4, 1,2,3,5,6,7, 1,2,3,5,6,7,
                                0,4,6,7, 1,5,7, 2,3,4,5,6,7, 6,7};

// ---------------- workspace layout (bytes) ----------------
// xt     f64 [T][B][NBAR][CCH]             81,788,928
// drive  f64 [TCH][B][NPOPS][NEUR]         81,788,928
// idx    i32 [T][B][NBAR][3]                1,916,928
// popT   f32 [NCONNS][NBAR][32c][32o]       5,910,528
// aggT   f32 [256][32]                         32,768
// cbias  f64 [NPOPS][NEUR]                     79,872
// alro   f64 [NPOPS*NEUR][2] (alpha,ro)       159,744
// stMem  f64 [B][NPOPS][NEUR]               5,111,808
// stB    f64 same                           5,111,808
// stProj f64 [B][NEUR]                        638,976
// stSp   u32 [B][NPOPS][NBAR]                  79,872
// total ~182.7 MB
#define OFS_XT     0
#define OFS_DRIVE  81788928
#define OFS_IDX    163577856
#define OFS_POPT   165494784
#define OFS_AGGT   171405312
#define OFS_CBIAS  171438080
#define OFS_ALRO   171517952
#define OFS_STMEM  171677696
#define OFS_STB    176789504
#define OFS_STPROJ 181901312
#define OFS_STSP   182540288

// ---------------- conv1d(2->64,k=3,s=2,p=1) -> xt f64 ----------------
__global__ __launch_bounds__(256) void kconv(const float* __restrict__ inp,
    const float* __restrict__ comp_w, const float* __restrict__ comp_b,
    double* __restrict__ xt)
{
  __shared__ float si[256];
  const int bn = blockIdx.x;            // b*NBAR + n
  const int b = bn / NBAR, n = bn % NBAR;
  const int tid = threadIdx.x;
  si[tid] = inp[bn*256 + tid];          // [2][128]
  __syncthreads();
  const int c = tid & 63, tq = tid >> 6;
  double wv[6];
  #pragma unroll
  for (int u = 0; u < 6; ++u) wv[u] = (double)comp_w[c*6 + u];
  const double cb = (double)comp_b[c];
  for (int t = tq; t < TSTEPS; t += 4) {
    const int p0 = 2*t - 1;             // taps p0, p0+1, p0+2  (p0+1,p0+2 always valid)
    double acc = cb;
    if (p0 >= 0) acc += (double)si[p0]     * wv[0];
    acc             += (double)si[p0+1]    * wv[1];
    acc             += (double)si[p0+2]    * wv[2];
    if (p0 >= 0) acc += (double)si[128+p0] * wv[3];
    acc             += (double)si[128+p0+1]* wv[4];
    acc             += (double)si[128+p0+2]* wv[5];
    xt[((t*BATCH + b)*NBAR + n)*CCH + c] = acc;
  }
}

// ---------------- weight transposes ----------------
__global__ __launch_bounds__(256) void kprepw(const float* __restrict__ pop_w,
    const float* __restrict__ agg_w, float* __restrict__ popT, float* __restrict__ aggT)
{
  const int e = blockIdx.x*256 + threadIdx.x;
  if (e < NCONNS*NBAR*1024) {
    const int o = e & 31, c = (e >> 5) & 31, nk = e >> 10;
    popT[e] = pop_w[nk*1024 + o*32 + c];      // [k][n][c][o] <- [k][n][o][c]
  }
  if (e < 256*32) aggT[e] = agg_w[(e & 31)*256 + (e >> 5)];  // [m][o] <- [o][m]
}

// ---------------- per-neuron constants: cbias, alpha, ro ----------------
__global__ __launch_bounds__(256) void kprepn(const float* __restrict__ th_b,
    const float* __restrict__ pop_b, const float* __restrict__ tau_adp,
    const float* __restrict__ tau_m, double* __restrict__ cbias, double* __restrict__ alro)
{
  const int e = blockIdx.x*256 + threadIdx.x;
  if (e >= NPOPS*NEUR) return;
  const int i = e / NEUR, r = e % NEUR;
  double cb = (double)th_b[e];
  const int no = C_NSRC[i], ofi = C_OFF[i];
  for (int jj = 0; jj < no; ++jj) cb += (double)pop_b[(ofi+jj)*NEUR + r];
  cbias[e] = cb;
  alro[2*e]   = exp(-1.0/(double)tau_m[e]);
  alro[2*e+1] = exp(-1.0/(double)tau_adp[e]);
}

// ---------------- similarity + top-3 (stable ties, lower index first) ----------------
__global__ __launch_bounds__(128) void ksim(const double* __restrict__ xt, int* __restrict__ idxg)
{
  __shared__ double sx[NBAR*CCH];
  __shared__ double simL[NBAR*NBAR];
  const int g = blockIdx.x;             // t*BATCH + b
  const int tid = threadIdx.x;
  const double* base = xt + (size_t)g*NBAR*CCH;
  for (int e = tid; e < NBAR*CCH; e += 128) sx[e] = base[e];
  __syncthreads();
  for (int p = tid; p < NBAR*NBAR; p += 128) {
    const int n = p / NBAR, m = p - n*NBAR;
    double acc = 0.0;
    #pragma unroll
    for (int c = 0; c < CCH; ++c) acc += sx[n*CCH+c]*sx[m*CCH+c];
    simL[p] = acc;
  }
  __syncthreads();
  if (tid < NBAR) {
    const double* row = simL + tid*NBAR;
    double v0=-1e300, v1=-1e300, v2=-1e300; int i0=0, i1=0, i2=0;
    for (int m = 0; m < NBAR; ++m) {
      const double v = row[m];
      if      (v > v0) { v2=v1;i2=i1; v1=v0;i1=i0; v0=v;i0=m; }
      else if (v > v1) { v2=v1;i2=i1; v1=v; i1=m; }
      else if (v > v2) { v2=v; i2=m; }
    }
    int* op = idxg + (g*NBAR + tid)*3;
    op[0]=i0; op[1]=i1; op[2]=i2;
  }
}

// ---------------- drive precompute: xt @ th_w[i,n]^T + cbias (f64) ----------------
__global__ __launch_bounds__(256) void kdrive(const double* __restrict__ xt,
    const float* __restrict__ th_w, const double* __restrict__ cbias,
    double* __restrict__ drive, int c0)
{
  __shared__ float  sw[32*65];          // padded, conflict-free
  __shared__ double sx8[8*CCH];
  const int bx = blockIdx.x;            // i*NBAR + n
  const int i = bx / NBAR, n = bx % NBAR;
  const int tid = threadIdx.x;
  const int o = tid & 31, rq = tid >> 5;
  for (int e = tid; e < 2048; e += 256) sw[(e>>6)*65 + (e&63)] = th_w[bx*2048 + e];
  const double cb = cbias[i*NEUR + n*PSZ + o];
  __syncthreads();
  for (int base = 0; base < TCH*BATCH; base += 8) {
    for (int e = tid; e < 512; e += 256) {
      const int rr = e >> 6, cc = e & 63;
      const int row = base + rr, tt = row >> 6, bb = row & 63;
      sx8[e] = xt[(((c0+tt)*BATCH + bb)*NBAR + n)*CCH + cc];
    }
    __syncthreads();
    double acc = cb;
    #pragma unroll
    for (int c = 0; c < CCH; ++c) acc += sx8[rq*CCH + c] * (double)sw[o*65 + c];
    drive[((base+rq)*NPOPS + i)*NEUR + n*PSZ + o] = acc;
    __syncthreads();
  }
}

// ---------------- recurrent core: 1 block per batch, 16 t-steps per launch ----------------
__global__ __launch_bounds__(768) void krec(
    const double* __restrict__ drv, const int* __restrict__ idxg,
    const float* __restrict__ popT, const float* __restrict__ aggTg,
    const float* __restrict__ agg_b, const double* __restrict__ alro,
    double* __restrict__ stMem, double* __restrict__ stB,
    double* __restrict__ stProj, unsigned* __restrict__ stSp,
    float* __restrict__ hOut, float* __restrict__ mOut, int t0)
{
  __shared__ double   proj[NBAR*PSZ];   //  9,984 B
  __shared__ float    aggT[256*PSZ];    // 32,768 B
  __shared__ unsigned spM[NPOPS*40];    //  1,280 B  (padded rows)
  const int b = blockIdx.x, tid = threadIdx.x;
  const int o = tid & 31, s = tid >> 5; // 24 half-wave slots
  const int n0 = s, n1 = s + 24;
  const bool h1 = (n1 < NBAR);          // s < 15

  for (int e = tid; e < 256*PSZ; e += 768) aggT[e] = aggTg[e];

  double mem[2][NPOPS], bbr[2][NPOPS];
  if (t0 == 0) {
    #pragma unroll
    for (int i = 0; i < NPOPS; ++i) { mem[0][i]=0.0; mem[1][i]=0.0; bbr[0][i]=0.0; bbr[1][i]=0.0; }
    for (int e = tid; e < NBAR*PSZ; e += 768) proj[e] = 0.0;
    for (int e = tid; e < NPOPS*40; e += 768) spM[e] = 0u;
  } else {
    #pragma unroll
    for (int i = 0; i < NPOPS; ++i) {
      mem[0][i] = stMem[(b*NPOPS+i)*NEUR + n0*PSZ + o];
      bbr[0][i] = stB  [(b*NPOPS+i)*NEUR + n0*PSZ + o];
      mem[1][i] = h1 ? stMem[(b*NPOPS+i)*NEUR + n1*PSZ + o] : 0.0;
      bbr[1][i] = h1 ? stB  [(b*NPOPS+i)*NEUR + n1*PSZ + o] : 0.0;
    }
    for (int e = tid; e < NBAR*PSZ; e += 768) proj[e] = stProj[b*NEUR + e];
    for (int e = tid; e < NPOPS*40; e += 768)
      spM[e] = ((e % 40) < NBAR) ? stSp[b*NPOPS*NBAR + (e/40)*NBAR + (e%40)] : 0u;
  }
  __syncthreads();
  const double aggBo = (double)agg_b[o];

  for (int tt = 0; tt < TCH; ++tt) {
    const int t = t0 + tt;
    int ia0[3], ia1[3];
    { const int* ip = idxg + ((t*BATCH+b)*NBAR + n0)*3; ia0[0]=ip[0]; ia0[1]=ip[1]; ia0[2]=ip[2]; }
    if (h1) { const int* ip = idxg + ((t*BATCH+b)*NBAR + n1)*3; ia1[0]=ip[0]; ia1[1]=ip[1]; ia1[2]=ip[2]; }
    else    { ia1[0]=ia1[1]=ia1[2]=0; }

    #pragma unroll
    for (int i = 0; i < NPOPS; ++i) {
      // ---- phase (a): accumulate cur for owned barrels (reads spM old/new mix + proj)
      const double* dp = drv + ((tt*BATCH + b)*NPOPS + i)*NEUR;
      double cur0 = dp[n0*PSZ + o];
      double cur1 = h1 ? dp[n1*PSZ + o] : 0.0;
      #pragma unroll
      for (int jj = 0; jj < C_NSRC[i]; ++jj) {
        const int k = C_OFF[i] + jj;
        const int j = C_SRCS[k];
        const float* colb = popT + k*(NBAR*1024);
        {
          unsigned msk = spM[j*40 + n0];
          const float* col = colb + n0*1024 + o;
          while (msk) { const int c = __ffs(msk)-1; msk &= msk-1; cur0 += (double)col[c*PSZ]; }
        }
        if (h1) {
          unsigned msk = spM[j*40 + n1];
          const float* col = colb + n1*1024 + o;
          while (msk) { const int c = __ffs(msk)-1; msk &= msk-1; cur1 += (double)col[c*PSZ]; }
        }
      }
      if (t > 0) {
        const double a0 = proj[ia0[0]*PSZ+o] + proj[ia0[1]*PSZ+o] + proj[ia0[2]*PSZ+o];
        cur0 += 0.1 * (a0/3.0 + aggBo);
        if (h1) {
          const double a1 = proj[ia1[0]*PSZ+o] + proj[ia1[1]*PSZ+o] + proj[ia1[2]*PSZ+o];
          cur1 += 0.1 * (a1/3.0 + aggBo);
        }
      }
      __syncthreads();   // all proj/spM reads done before any update

      // ---- phase (b): neuron update, spike ballot, outputs, proj delta
      #pragma unroll
      for (int q = 0; q < 2; ++q) {
        const int n = q ? n1 : n0;
        const bool act = (q == 0) || h1;
        const double cu = q ? cur1 : cur0;
        unsigned oldM = 0; int spk = 0;
        if (act) {
          const int e = i*NEUR + n*PSZ + o;
          const double al = alro[2*e], ro = alro[2*e+1];
          oldM = spM[i*40 + n];
          const double sOld = (double)((oldM >> o) & 1u);
          const double bn  = ro*bbr[q][i] + (1.0-ro)*sOld;
          const double Bth = 0.02 + 1.8*bn;
          const double mN  = (q ? mem[1][i] : mem[0][i])*al + (1.0-al)*cu;
          spk = (mN - Bth) > 0.0;
          const double mF = mN - Bth*(double)spk;
          if (q) { mem[1][i]=mF; bbr[1][i]=bn; } else { mem[0][i]=mF; bbr[0][i]=bn; }
          const int ob = ((b*TSTEPS + t)*NBAR + n)*256 + i*PSZ + o;
          hOut[ob] = (float)spk;
          mOut[ob] = (float)mN;   // pre-reset membrane == mem + s*Bth
        }
        const unsigned long long bal = __ballot(act && spk);
        if (act) {
          const unsigned newM = (tid & 32) ? (unsigned)(bal >> 32) : (unsigned)(bal & 0xffffffffULL);
          if (o == 0) spM[i*40 + n] = newM;
          unsigned diff = newM ^ oldM;
          double pv = proj[n*PSZ + o];
          while (diff) {
            const int c = __ffs(diff)-1; diff &= diff-1;
            const double w = (double)aggT[(i*PSZ + c)*PSZ + o];
            pv += ((newM >> c) & 1u) ? w : -w;
          }
          proj[n*PSZ + o] = pv;
        }
      }
      __syncthreads();   // spikes/proj visible for next population
    }
  }

  // persist state across chunks
  #pragma unroll
  for (int i = 0; i < NPOPS; ++i) {
    stMem[(b*NPOPS+i)*NEUR + n0*PSZ + o] = mem[0][i];
    stB  [(b*NPOPS+i)*NEUR + n0*PSZ + o] = bbr[0][i];
    if (h1) {
      stMem[(b*NPOPS+i)*NEUR + n1*PSZ + o] = mem[1][i];
      stB  [(b*NPOPS+i)*NEUR + n1*PSZ + o] = bbr[1][i];
    }
  }
  for (int e = tid; e < NEUR; e += 768) stProj[b*NEUR + e] = proj[e];
  for (int e = tid; e < NPOPS*NBAR; e += 768) stSp[b*NPOPS*NBAR + e] = spM[(e/NBAR)*40 + (e%NBAR)];
}

// ---------------- readout: mean L5 over (t,n) -> linear -> softmax ----------------
__global__ __launch_bounds__(256) void kread(const float* __restrict__ hBase,
    const float* __restrict__ ro_w, const float* __restrict__ ro_b, float* __restrict__ outp)
{
  __shared__ double part[2][128];
  __shared__ double meanv[128];
  __shared__ double lg[36];
  const int b = blockIdx.x, tid = threadIdx.x;
  const int d = tid & 127, half = tid >> 7;
  double acc = 0.0;
  for (int r = half*1248; r < half*1248 + 1248; ++r)   // r = t*NBAR + n, 2496 total
    acc += (double)hBase[((size_t)b*2496 + r)*256 + 128 + d];
  part[half][d] = acc;
  __syncthreads();
  if (tid < 128) meanv[tid] = (part[0][tid] + part[1][tid]) / 2496.0;
  __syncthreads();
  if (tid < 36) {
    double a = (double)ro_b[tid];
    for (int e = 0; e < 128; ++e) a += meanv[e]*(double)ro_w[tid*128 + e];
    lg[tid] = a;
  }
  __syncthreads();
  if (tid == 0) {
    double mx = lg[0];
    for (int dd = 1; dd < 36; ++dd) mx = fmax(mx, lg[dd]);
    double ex[36]; double sum = 0.0;
    for (int dd = 0; dd < 36; ++dd) { ex[dd] = exp(lg[dd]-mx); sum += ex[dd]; }
    for (int dd = 0; dd < 36; ++dd) outp[b*36 + dd] = (float)(ex[dd]/sum);
  }
}

// ---------------- launcher ----------------
extern "C" void kernel_launch(void* const* d_in, const int* in_sizes, int n_in,
                              void* d_out, int out_size, void* d_ws, size_t ws_size,
                              hipStream_t stream)
{
  const float* inp     = (const float*)d_in[0];
  const float* comp_w  = (const float*)d_in[1];
  const float* comp_b  = (const float*)d_in[2];
  const float* th_w    = (const float*)d_in[3];
  const float* th_b    = (const float*)d_in[4];
  const float* pop_w   = (const float*)d_in[5];
  const float* pop_b   = (const float*)d_in[6];
  const float* tau_adp = (const float*)d_in[7];
  const float* tau_m   = (const float*)d_in[8];
  const float* agg_w   = (const float*)d_in[9];
  const float* agg_b   = (const float*)d_in[10];
  const float* ro_w    = (const float*)d_in[11];
  const float* ro_b    = (const float*)d_in[12];

  char* ws = (char*)d_ws;
  double*   xt     = (double*)  (ws + OFS_XT);
  double*   drive  = (double*)  (ws + OFS_DRIVE);
  int*      idxg   = (int*)     (ws + OFS_IDX);
  float*    popT   = (float*)   (ws + OFS_POPT);
  float*    aggT   = (float*)   (ws + OFS_AGGT);
  double*   cbias  = (double*)  (ws + OFS_CBIAS);
  double*   alro   = (double*)  (ws + OFS_ALRO);
  double*   stMem  = (double*)  (ws + OFS_STMEM);
  double*   stB    = (double*)  (ws + OFS_STB);
  double*   stProj = (double*)  (ws + OFS_STPROJ);
  unsigned* stSp   = (unsigned*)(ws + OFS_STSP);

  float* outp = (float*)d_out;                 // (64,36) softmax
  float* hOut = outp + 64*36;                  // (64,64,39,256)
  float* mOut = hOut + 64*64*39*256;           // (64,64,39,256)

  kconv <<<BATCH*NBAR, 256, 0, stream>>>(inp, comp_w, comp_b, xt);
  kprepw<<<5772, 256, 0, stream>>>(pop_w, agg_w, popT, aggT);
  kprepn<<<39, 256, 0, stream>>>(th_b, pop_b, tau_adp, tau_m, cbias, alro);
  ksim  <<<TSTEPS*BATCH, 128, 0, stream>>>(xt, idxg);
  for (int c0 = 0; c0 < TSTEPS; c0 += TCH) {
    kdrive<<<NPOPS*NBAR, 256, 0, stream>>>(xt, th_w, cbias, drive, c0);
    krec  <<<BATCH, 768, 0, stream>>>(drive, idxg, popT, aggT, agg_b, alro,
                                      stMem, stB, stProj, stSp, hOut, mOut, c0);
  }
  kread <<<BATCH, 256, 0, stream>>>(hOut, ro_w, ro_b, outp);
}

// Round 2
// 6475.336 us; speedup vs baseline: 1.1425x; 1.1425x over previous
//
#include <hip/hip_runtime.h>
#include <math.h>

// ---------------- problem constants ----------------
#define NBAR   39
#define NPOPS  8
#define PSZ    32
#define TSTEPS 64
#define BATCH  64
#define CCH    64              // compressed channels
#define NEUR   (NBAR*PSZ)      // 1248
#define NCONNS 37
#define TCH    16              // time chunk (4 chunks of 16)
#define ZPAD   46176           // index of zero-weight pad column in popT

// connectivity: SRC[i] = rows j with ALLTOALL[j][i] != 0
constexpr int C_NSRC[NPOPS] = {5,5,6,6,4,3,6,2};
constexpr int C_OFF [NPOPS] = {0,5,10,16,22,26,29,35};
constexpr int C_SRCS[NCONNS] = {0,1,2,3,4, 0,1,2,3,4, 1,2,3,5,6,7, 1,2,3,5,6,7,
                                0,4,6,7, 1,5,7, 2,3,4,5,6,7, 6,7};

// ---------------- workspace layout (bytes) ----------------
#define OFS_XT     0
#define OFS_DRIVE  81788928
#define OFS_IDX    163577856
#define OFS_POPT   165494784   // floats: 37*39*1024 + 32 zero-pad = 1,477,664
#define OFS_AGGT   171406336
#define OFS_CBIAS  171439104
#define OFS_ALRO   171518976
#define OFS_STMEM  171678720
#define OFS_STB    176790528
#define OFS_STPROJ 181902336
#define OFS_STSP   182541312
// end ~182.62 MB

// ---------------- conv1d(2->64,k=3,s=2,p=1) -> xt f64 ----------------
__global__ __launch_bounds__(256) void kconv(const float* __restrict__ inp,
    const float* __restrict__ comp_w, const float* __restrict__ comp_b,
    double* __restrict__ xt)
{
  __shared__ float si[256];
  const int bn = blockIdx.x;            // b*NBAR + n
  const int b = bn / NBAR, n = bn % NBAR;
  const int tid = threadIdx.x;
  si[tid] = inp[bn*256 + tid];          // [2][128]
  __syncthreads();
  const int c = tid & 63, tq = tid >> 6;
  double wv[6];
  #pragma unroll
  for (int u = 0; u < 6; ++u) wv[u] = (double)comp_w[c*6 + u];
  const double cb = (double)comp_b[c];
  for (int t = tq; t < TSTEPS; t += 4) {
    const int p0 = 2*t - 1;
    double acc = cb;
    if (p0 >= 0) acc += (double)si[p0]     * wv[0];
    acc             += (double)si[p0+1]    * wv[1];
    acc             += (double)si[p0+2]    * wv[2];
    if (p0 >= 0) acc += (double)si[128+p0] * wv[3];
    acc             += (double)si[128+p0+1]* wv[4];
    acc             += (double)si[128+p0+2]* wv[5];
    xt[((t*BATCH + b)*NBAR + n)*CCH + c] = acc;
  }
}

// ---------------- weight transposes ----------------
__global__ __launch_bounds__(256) void kprepw(const float* __restrict__ pop_w,
    const float* __restrict__ agg_w, float* __restrict__ popT, float* __restrict__ aggT)
{
  const int e = blockIdx.x*256 + threadIdx.x;
  if (e < NCONNS*NBAR*1024) {
    const int o = e & 31, c = (e >> 5) & 31, nk = e >> 10;
    popT[e] = pop_w[nk*1024 + o*32 + c];      // [k][n][c][o] <- [k][n][o][c]
  }
  if (e < 32) popT[NCONNS*NBAR*1024 + e] = 0.0f;   // zero pad column (ZPAD)
  if (e < 256*32) aggT[e] = agg_w[(e & 31)*256 + (e >> 5)];  // [m][o] <- [o][m]
}

// ---------------- per-neuron constants ----------------
__global__ __launch_bounds__(256) void kprepn(const float* __restrict__ th_b,
    const float* __restrict__ pop_b, const float* __restrict__ tau_adp,
    const float* __restrict__ tau_m, double* __restrict__ cbias, double* __restrict__ alro)
{
  const int e = blockIdx.x*256 + threadIdx.x;
  if (e >= NPOPS*NEUR) return;
  const int i = e / NEUR, r = e % NEUR;
  double cb = (double)th_b[e];
  const int no = C_NSRC[i], ofi = C_OFF[i];
  for (int jj = 0; jj < no; ++jj) cb += (double)pop_b[(ofi+jj)*NEUR + r];
  cbias[e] = cb;
  alro[2*e]   = exp(-1.0/(double)tau_m[e]);
  alro[2*e+1] = exp(-1.0/(double)tau_adp[e]);
}

// ---------------- similarity + top-3 ----------------
__global__ __launch_bounds__(128) void ksim(const double* __restrict__ xt, int* __restrict__ idxg)
{
  __shared__ double sx[NBAR*CCH];
  __shared__ double simL[NBAR*NBAR];
  const int g = blockIdx.x;             // t*BATCH + b
  const int tid = threadIdx.x;
  const double* base = xt + (size_t)g*NBAR*CCH;
  for (int e = tid; e < NBAR*CCH; e += 128) sx[e] = base[e];
  __syncthreads();
  for (int p = tid; p < NBAR*NBAR; p += 128) {
    const int n = p / NBAR, m = p - n*NBAR;
    double acc = 0.0;
    #pragma unroll
    for (int c = 0; c < CCH; ++c) acc += sx[n*CCH+c]*sx[m*CCH+c];
    simL[p] = acc;
  }
  __syncthreads();
  if (tid < NBAR) {
    const double* row = simL + tid*NBAR;
    double v0=-1e300, v1=-1e300, v2=-1e300; int i0=0, i1=0, i2=0;
    for (int m = 0; m < NBAR; ++m) {
      const double v = row[m];
      if      (v > v0) { v2=v1;i2=i1; v1=v0;i1=i0; v0=v;i0=m; }
      else if (v > v1) { v2=v1;i2=i1; v1=v; i1=m; }
      else if (v > v2) { v2=v; i2=m; }
    }
    int* op = idxg + (g*NBAR + tid)*3;
    op[0]=i0; op[1]=i1; op[2]=i2;
  }
}

// ---------------- drive precompute: xt @ th_w[i,n]^T + cbias (f64) ----------------
__global__ __launch_bounds__(256) void kdrive(const double* __restrict__ xt,
    const float* __restrict__ th_w, const double* __restrict__ cbias,
    double* __restrict__ drive, int c0)
{
  __shared__ float  sw[32*65];
  __shared__ double sx8[8*CCH];
  const int bx = blockIdx.x;            // i*NBAR + n
  const int i = bx / NBAR, n = bx % NBAR;
  const int tid = threadIdx.x;
  const int o = tid & 31, rq = tid >> 5;
  for (int e = tid; e < 2048; e += 256) sw[(e>>6)*65 + (e&63)] = th_w[bx*2048 + e];
  const double cb = cbias[i*NEUR + n*PSZ + o];
  __syncthreads();
  for (int base = 0; base < TCH*BATCH; base += 8) {
    for (int e = tid; e < 512; e += 256) {
      const int rr = e >> 6, cc = e & 63;
      const int row = base + rr, tt = row >> 6, bb = row & 63;
      sx8[e] = xt[(((c0+tt)*BATCH + bb)*NBAR + n)*CCH + cc];
    }
    __syncthreads();
    double acc = cb;
    #pragma unroll
    for (int c = 0; c < CCH; ++c) acc += sx8[rq*CCH + c] * (double)sw[o*65 + c];
    drive[((base+rq)*NPOPS + i)*NEUR + n*PSZ + o] = acc;
    __syncthreads();
  }
}

// 16-wide gather step: WORD holds two u16 popT column indices
#define GSTEP(WORD, A, B) { const unsigned xx_ = (WORD); \
  const float vA_ = pTo[(int)((xx_ & 0xffffu) << 5)]; \
  const float vB_ = pTo[(int)((xx_ >> 16) << 5)]; \
  A += (double)vA_; B += (double)vB_; }

// ---------------- recurrent core ----------------
__global__ __launch_bounds__(768) void krec(
    const double* __restrict__ drv, const int* __restrict__ idxg,
    const float* __restrict__ popTg, const float* __restrict__ aggTg,
    const float* __restrict__ agg_b, const double* __restrict__ alro,
    double* __restrict__ stMem, double* __restrict__ stB,
    double* __restrict__ stProj, unsigned* __restrict__ stSp,
    float* __restrict__ hOut, float* __restrict__ mOut, int t0)
{
  __shared__ double   proj[NBAR*PSZ];                         //  9,984 B
  __shared__ float    aggT[256*PSZ];                          // 32,768 B
  __shared__ unsigned spM[NPOPS*40];                          //  1,280 B
  __shared__ __attribute__((aligned(16))) unsigned short lst[24][2][208]; // 19,968 B
  const int b = blockIdx.x, tid = threadIdx.x;
  const int o = tid & 31, s = tid >> 5; // 24 half-wave groups
  const int n0 = s, n1 = s + 24;
  const bool h1 = (n1 < NBAR);
  const unsigned ltm = (1u << o) - 1u;
  const float* pTo = popTg + o;

  for (int e = tid; e < 256*PSZ; e += 768) aggT[e] = aggTg[e];

  double mem[2][NPOPS], bbr[2][NPOPS];
  if (t0 == 0) {
    #pragma unroll
    for (int i = 0; i < NPOPS; ++i) { mem[0][i]=0.0; mem[1][i]=0.0; bbr[0][i]=0.0; bbr[1][i]=0.0; }
    for (int e = tid; e < NBAR*PSZ; e += 768) proj[e] = 0.0;
    for (int e = tid; e < NPOPS*40; e += 768) spM[e] = 0u;
  } else {
    #pragma unroll
    for (int i = 0; i < NPOPS; ++i) {
      mem[0][i] = stMem[(b*NPOPS+i)*NEUR + n0*PSZ + o];
      bbr[0][i] = stB  [(b*NPOPS+i)*NEUR + n0*PSZ + o];
      mem[1][i] = h1 ? stMem[(b*NPOPS+i)*NEUR + n1*PSZ + o] : 0.0;
      bbr[1][i] = h1 ? stB  [(b*NPOPS+i)*NEUR + n1*PSZ + o] : 0.0;
    }
    for (int e = tid; e < NBAR*PSZ; e += 768) proj[e] = stProj[b*NEUR + e];
    for (int e = tid; e < NPOPS*40; e += 768)
      spM[e] = ((e % 40) < NBAR) ? stSp[b*NPOPS*NBAR + (e/40)*NBAR + (e%40)] : 0u;
  }
  __syncthreads();
  const double aggBo = (double)agg_b[o];

  #pragma unroll 1
  for (int tt = 0; tt < TCH; ++tt) {
    const int t = t0 + tt;
    // prefetch this timestep's drive for all pops (16 independent loads)
    const double* drvT = drv + ((size_t)(tt*BATCH + b))*NPOPS*NEUR;
    double dv0[NPOPS], dv1[NPOPS];
    #pragma unroll
    for (int i = 0; i < NPOPS; ++i) {
      dv0[i] = drvT[i*NEUR + n0*PSZ + o];
      dv1[i] = h1 ? drvT[i*NEUR + n1*PSZ + o] : 0.0;
    }
    int ia0[3], ia1[3];
    { const int* ip = idxg + ((t*BATCH+b)*NBAR + n0)*3; ia0[0]=ip[0]; ia0[1]=ip[1]; ia0[2]=ip[2]; }
    if (h1) { const int* ip = idxg + ((t*BATCH+b)*NBAR + n1)*3; ia1[0]=ip[0]; ia1[1]=ip[1]; ia1[2]=ip[2]; }
    else    { ia1[0]=ia1[1]=ia1[2]=0; }

    #pragma unroll
    for (int i = 0; i < NPOPS; ++i) {
      // prefetch phase-b constants early (latency hidden under gather)
      const int eA = i*NEUR + n0*PSZ + o;
      const int eB = i*NEUR + n1*PSZ + o;
      const double al0 = alro[2*eA], ro0 = alro[2*eA+1];
      const double al1 = h1 ? alro[2*eB]   : 0.0;
      const double ro1 = h1 ? alro[2*eB+1] : 0.0;

      // ---- phase (a): build compacted spike-column lists, then wide gather
      double cur0 = dv0[i], cur1 = dv1[i];
      if (t > 0) {
        const double a0 = proj[ia0[0]*PSZ+o] + proj[ia0[1]*PSZ+o] + proj[ia0[2]*PSZ+o];
        cur0 += 0.1 * (a0/3.0 + aggBo);
        if (h1) {
          const double a1 = proj[ia1[0]*PSZ+o] + proj[ia1[1]*PSZ+o] + proj[ia1[2]*PSZ+o];
          cur1 += 0.1 * (a1/3.0 + aggBo);
        }
      }
      unsigned c0 = 0, c1 = 0;
      #pragma unroll
      for (int jj = 0; jj < C_NSRC[i]; ++jj) {
        const int k = C_OFF[i] + jj;
        const int j = C_SRCS[k];
        const unsigned m0 = spM[j*40 + n0];
        if ((m0 >> o) & 1u)
          lst[s][0][c0 + __popc(m0 & ltm)] = (unsigned short)(((k*NBAR + n0) << 5) | o);
        c0 += (unsigned)__popc(m0);
        if (h1) {
          const unsigned m1 = spM[j*40 + n1];
          if ((m1 >> o) & 1u)
            lst[s][1][c1 + __popc(m1 & ltm)] = (unsigned short)(((k*NBAR + n1) << 5) | o);
          c1 += (unsigned)__popc(m1);
        }
      }
      if (o < 16) { lst[s][0][c0 + o] = (unsigned short)ZPAD;
                    lst[s][1][c1 + o] = (unsigned short)ZPAD; }
      // gather list 0 -> cur0
      if (c0 > 0) {
        double a0=0,a1=0,a2=0,a3=0,a4=0,a5=0,a6=0,a7=0;
        for (unsigned p = 0; p < c0; p += 16) {
          const uint4* lp = (const uint4*)&lst[s][0][p];
          const uint4 w0 = lp[0], w1 = lp[1];
          GSTEP(w0.x, a0, a1); GSTEP(w0.y, a2, a3);
          GSTEP(w0.z, a4, a5); GSTEP(w0.w, a6, a7);
          GSTEP(w1.x, a0, a1); GSTEP(w1.y, a2, a3);
          GSTEP(w1.z, a4, a5); GSTEP(w1.w, a6, a7);
        }
        cur0 += ((a0+a1)+(a2+a3)) + ((a4+a5)+(a6+a7));
      }
      // gather list 1 -> cur1
      if (h1 && c1 > 0) {
        double a0=0,a1=0,a2=0,a3=0,a4=0,a5=0,a6=0,a7=0;
        for (unsigned p = 0; p < c1; p += 16) {
          const uint4* lp = (const uint4*)&lst[s][1][p];
          const uint4 w0 = lp[0], w1 = lp[1];
          GSTEP(w0.x, a0, a1); GSTEP(w0.y, a2, a3);
          GSTEP(w0.z, a4, a5); GSTEP(w0.w, a6, a7);
          GSTEP(w1.x, a0, a1); GSTEP(w1.y, a2, a3);
          GSTEP(w1.z, a4, a5); GSTEP(w1.w, a6, a7);
        }
        cur1 += ((a0+a1)+(a2+a3)) + ((a4+a5)+(a6+a7));
      }
      __syncthreads();   // all proj/spM reads done before any update

      // ---- phase (b): neuron update, spike ballot, outputs, proj delta
      #pragma unroll
      for (int q = 0; q < 2; ++q) {
        const int n = q ? n1 : n0;
        const bool act = (q == 0) || h1;
        const double cu = q ? cur1 : cur0;
        unsigned oldM = 0; int spk = 0;
        if (act) {
          const double al = q ? al1 : al0;
          const double ro = q ? ro1 : ro0;
          oldM = spM[i*40 + n];
          const double sOld = (double)((oldM >> o) & 1u);
          const double bn  = ro*bbr[q][i] + (1.0-ro)*sOld;
          const double Bth = 0.02 + 1.8*bn;
          const double mN  = (q ? mem[1][i] : mem[0][i])*al + (1.0-al)*cu;
          spk = (mN - Bth) > 0.0;
          const double mF = mN - Bth*(double)spk;
          if (q) { mem[1][i]=mF; bbr[1][i]=bn; } else { mem[0][i]=mF; bbr[0][i]=bn; }
          const int ob = ((b*TSTEPS + t)*NBAR + n)*256 + i*PSZ + o;
          hOut[ob] = (float)spk;
          mOut[ob] = (float)mN;
        }
        const unsigned long long bal = __ballot(act && spk);
        if (act) {
          const unsigned newM = (tid & 32) ? (unsigned)(bal >> 32) : (unsigned)(bal & 0xffffffffULL);
          if (o == 0) spM[i*40 + n] = newM;
          unsigned diff = newM ^ oldM;
          double pv = proj[n*PSZ + o];
          while (diff) {
            unsigned d = diff;
            const int cA = __ffs(d)-1; d &= d-1;
            const bool hB = d!=0; const int cB = hB ? __ffs(d)-1 : cA; d &= d-1;
            const bool hC = d!=0; const int cC = hC ? __ffs(d)-1 : cA; d &= d-1;
            const bool hD = d!=0; const int cD = hD ? __ffs(d)-1 : cA; d &= d-1;
            diff = d;
            const double wA = (double)aggT[(i*PSZ+cA)*PSZ+o];
            const double wB = (double)aggT[(i*PSZ+cB)*PSZ+o];
            const double wC = (double)aggT[(i*PSZ+cC)*PSZ+o];
            const double wD = (double)aggT[(i*PSZ+cD)*PSZ+o];
            const double sA = ((newM>>cA)&1u) ? wA : -wA;
            const double sB = ((newM>>cB)&1u) ? wB : -wB;
            const double sC = ((newM>>cC)&1u) ? wC : -wC;
            const double sD = ((newM>>cD)&1u) ? wD : -wD;
            pv += sA;
            pv += hB ? sB : 0.0;
            pv += hC ? sC : 0.0;
            pv += hD ? sD : 0.0;
          }
          proj[n*PSZ + o] = pv;
        }
      }
      __syncthreads();   // spikes/proj visible for next population
    }
  }

  // persist state across chunks
  #pragma unroll
  for (int i = 0; i < NPOPS; ++i) {
    stMem[(b*NPOPS+i)*NEUR + n0*PSZ + o] = mem[0][i];
    stB  [(b*NPOPS+i)*NEUR + n0*PSZ + o] = bbr[0][i];
    if (h1) {
      stMem[(b*NPOPS+i)*NEUR + n1*PSZ + o] = mem[1][i];
      stB  [(b*NPOPS+i)*NEUR + n1*PSZ + o] = bbr[1][i];
    }
  }
  for (int e = tid; e < NEUR; e += 768) stProj[b*NEUR + e] = proj[e];
  for (int e = tid; e < NPOPS*NBAR; e += 768) stSp[b*NPOPS*NBAR + e] = spM[(e/NBAR)*40 + (e%NBAR)];
}

// ---------------- readout ----------------
__global__ __launch_bounds__(256) void kread(const float* __restrict__ hBase,
    const float* __restrict__ ro_w, const float* __restrict__ ro_b, float* __restrict__ outp)
{
  __shared__ double part[2][128];
  __shared__ double meanv[128];
  __shared__ double lg[36];
  const int b = blockIdx.x, tid = threadIdx.x;
  const int d = tid & 127, half = tid >> 7;
  double acc = 0.0;
  for (int r = half*1248; r < half*1248 + 1248; ++r)
    acc += (double)hBase[((size_t)b*2496 + r)*256 + 128 + d];
  part[half][d] = acc;
  __syncthreads();
  if (tid < 128) meanv[tid] = (part[0][tid] + part[1][tid]) / 2496.0;
  __syncthreads();
  if (tid < 36) {
    double a = (double)ro_b[tid];
    for (int e = 0; e < 128; ++e) a += meanv[e]*(double)ro_w[tid*128 + e];
    lg[tid] = a;
  }
  __syncthreads();
  if (tid == 0) {
    double mx = lg[0];
    for (int dd = 1; dd < 36; ++dd) mx = fmax(mx, lg[dd]);
    double ex[36]; double sum = 0.0;
    for (int dd = 0; dd < 36; ++dd) { ex[dd] = exp(lg[dd]-mx); sum += ex[dd]; }
    for (int dd = 0; dd < 36; ++dd) outp[b*36 + dd] = (float)(ex[dd]/sum);
  }
}

// ---------------- launcher ----------------
extern "C" void kernel_launch(void* const* d_in, const int* in_sizes, int n_in,
                              void* d_out, int out_size, void* d_ws, size_t ws_size,
                              hipStream_t stream)
{
  const float* inp     = (const float*)d_in[0];
  const float* comp_w  = (const float*)d_in[1];
  const float* comp_b  = (const float*)d_in[2];
  const float* th_w    = (const float*)d_in[3];
  const float* th_b    = (const float*)d_in[4];
  const float* pop_w   = (const float*)d_in[5];
  const float* pop_b   = (const float*)d_in[6];
  const float* tau_adp = (const float*)d_in[7];
  const float* tau_m   = (const float*)d_in[8];
  const float* agg_w   = (const float*)d_in[9];
  const float* agg_b   = (const float*)d_in[10];
  const float* ro_w    = (const float*)d_in[11];
  const float* ro_b    = (const float*)d_in[12];

  char* ws = (char*)d_ws;
  double*   xt     = (double*)  (ws + OFS_XT);
  double*   drive  = (double*)  (ws + OFS_DRIVE);
  int*      idxg   = (int*)     (ws + OFS_IDX);
  float*    popT   = (float*)   (ws + OFS_POPT);
  float*    aggT   = (float*)   (ws + OFS_AGGT);
  double*   cbias  = (double*)  (ws + OFS_CBIAS);
  double*   alro   = (double*)  (ws + OFS_ALRO);
  double*   stMem  = (double*)  (ws + OFS_STMEM);
  double*   stB    = (double*)  (ws + OFS_STB);
  double*   stProj = (double*)  (ws + OFS_STPROJ);
  unsigned* stSp   = (unsigned*)(ws + OFS_STSP);

  float* outp = (float*)d_out;                 // (64,36) softmax
  float* hOut = outp + 64*36;                  // (64,64,39,256)
  float* mOut = hOut + 64*64*39*256;           // (64,64,39,256)

  kconv <<<BATCH*NBAR, 256, 0, stream>>>(inp, comp_w, comp_b, xt);
  kprepw<<<5772, 256, 0, stream>>>(pop_w, agg_w, popT, aggT);
  kprepn<<<39, 256, 0, stream>>>(th_b, pop_b, tau_adp, tau_m, cbias, alro);
  ksim  <<<TSTEPS*BATCH, 128, 0, stream>>>(xt, idxg);
  for (int c0 = 0; c0 < TSTEPS; c0 += TCH) {
    kdrive<<<NPOPS*NBAR, 256, 0, stream>>>(xt, th_w, cbias, drive, c0);
    krec  <<<BATCH, 768, 0, stream>>>(drive, idxg, popT, aggT, agg_b, alro,
                                      stMem, stB, stProj, stSp, hOut, mOut, c0);
  }
  kread <<<BATCH, 256, 0, stream>>>(hOut, ro_w, ro_b, outp);
}

// Round 3
// 4532.035 us; speedup vs baseline: 1.6323x; 1.4288x over previous
//
#include <hip/hip_runtime.h>
#include <math.h>

// ---------------- problem constants ----------------
#define NBAR   39
#define NPOPS  8
#define PSZ    32
#define TSTEPS 64
#define BATCH  64
#define CCH    64
#define NEUR   (NBAR*PSZ)      // 1248
#define NCONNS 37
#define TCH    8               // time chunk (8 chunks of 8)

// connectivity
constexpr int C_NSRC[NPOPS] = {5,5,6,6,4,3,6,2};
constexpr int C_OFF [NPOPS] = {0,5,10,16,22,26,29,35};

// source-grouped tables: for source pop j, its target pops (ascending) and the
// connection index k supplying weights pop_w[k] for (source j -> target i).
constexpr int G_NT  [NPOPS] = {3,5,5,5,4,4,5,6};          // #targets of source j
constexpr int G_CUM [NPOPS] = {0,3,8,13,18,22,26,31};     // prefix into flat lists
constexpr int G_TGT [NCONNS] = {0,1,4,  0,1,2,3,5,  0,1,2,3,6,  0,1,2,3,6,
                                0,1,4,6,  2,3,5,6,  2,3,4,6,7,  2,3,4,5,6,7};
constexpr int G_K   [NCONNS] = {0,5,22, 1,6,10,16,26, 2,7,11,17,29, 3,8,12,18,30,
                                4,9,23,31, 13,19,27,32, 14,20,24,33,35, 15,21,25,28,34,36};
// region j: 1249 flat (n*32+c) slots (incl. zero-pad slot 1248) x NT x 32 floats
constexpr int G_OFFW[NPOPS] = {0,119904,319744,519584,719424,879296,1039168,1239008};

// ---------------- workspace layout (bytes) ----------------
#define OFS_XT     0           // f64 [T][B][NBAR][CCH]        81,788,928
#define OFS_DRIVE  81788928    // f64 [TCH][B][NPOPS][NEUR]    40,894,464
#define OFS_IDX    122683392   // i32 [T][B][NBAR][3]           1,916,928
#define OFS_GW     124600320   // f32 grouped weights           5,915,264
#define OFS_AGGT   130515584   // f32 [256][32]                    32,768
#define OFS_CBIAS  130548352   // f64 [NPOPS][NEUR]                79,872
#define OFS_ALRO   130628224   // f64 [NPOPS*NEUR][2]             159,744
#define OFS_MEMG   130787968   // f64 [B][NPOPS][NEUR]          5,111,808
#define OFS_BBRG   135899776   // f64 same                      5,111,808
#define OFS_ACCG   141011584   // f64 same                      5,111,808
#define OFS_STPROJ 146123392   // f64 [B][NEUR]                   638,976
#define OFS_STSP   146762368   // u32 [B][NPOPS][NBAR]             79,872
// end ~146.8 MB

// ---------------- conv1d(2->64,k=3,s=2,p=1) -> xt f64 ----------------
__global__ __launch_bounds__(256) void kconv(const float* __restrict__ inp,
    const float* __restrict__ comp_w, const float* __restrict__ comp_b,
    double* __restrict__ xt)
{
  __shared__ float si[256];
  const int bn = blockIdx.x;
  const int b = bn / NBAR, n = bn % NBAR;
  const int tid = threadIdx.x;
  si[tid] = inp[bn*256 + tid];
  __syncthreads();
  const int c = tid & 63, tq = tid >> 6;
  double wv[6];
  #pragma unroll
  for (int u = 0; u < 6; ++u) wv[u] = (double)comp_w[c*6 + u];
  const double cb = (double)comp_b[c];
  for (int t = tq; t < TSTEPS; t += 4) {
    const int p0 = 2*t - 1;
    double acc = cb;
    if (p0 >= 0) acc += (double)si[p0]     * wv[0];
    acc             += (double)si[p0+1]    * wv[1];
    acc             += (double)si[p0+2]    * wv[2];
    if (p0 >= 0) acc += (double)si[128+p0] * wv[3];
    acc             += (double)si[128+p0+1]* wv[4];
    acc             += (double)si[128+p0+2]* wv[5];
    xt[((t*BATCH + b)*NBAR + n)*CCH + c] = acc;
  }
}

// ---------------- grouped-weight build ----------------
__global__ __launch_bounds__(256) void kprepw(const float* __restrict__ pop_w,
    float* __restrict__ gw)
{
  const int bx = blockIdx.x;          // j*NBAR + n
  const int j = bx / NBAR, n = bx % NBAR;
  const int NT = G_NT[j];
  const int total = NT*1024;
  for (int e = threadIdx.x; e < total; e += 256) {
    const int c = e / (NT*32), r = e % (NT*32), tt = r >> 5, oo = r & 31;
    const int k = G_K[G_CUM[j]+tt];
    gw[G_OFFW[j] + (n*32+c)*NT*32 + tt*32 + oo] = pop_w[k*39936 + n*1024 + oo*32 + c];
  }
  if (n == 0)
    for (int e = threadIdx.x; e < NT*32; e += 256)
      gw[G_OFFW[j] + 1248*NT*32 + e] = 0.0f;   // zero-pad flat slot
}

// ---------------- per-neuron constants + aggT transpose ----------------
__global__ __launch_bounds__(256) void kprepn(const float* __restrict__ th_b,
    const float* __restrict__ pop_b, const float* __restrict__ tau_adp,
    const float* __restrict__ tau_m, const float* __restrict__ agg_w,
    double* __restrict__ cbias, double* __restrict__ alro, float* __restrict__ aggT)
{
  const int e = blockIdx.x*256 + threadIdx.x;
  if (e < 8192) aggT[e] = agg_w[(e & 31)*256 + (e >> 5)];   // [m][o] <- [o][m]
  if (e >= NPOPS*NEUR) return;
  const int i = e / NEUR, r = e % NEUR;
  double cb = (double)th_b[e];
  const int no = C_NSRC[i], ofi = C_OFF[i];
  for (int jj = 0; jj < no; ++jj) cb += (double)pop_b[(ofi+jj)*NEUR + r];
  cbias[e] = cb;
  alro[2*e]   = exp(-1.0/(double)tau_m[e]);
  alro[2*e+1] = exp(-1.0/(double)tau_adp[e]);
}

// ---------------- similarity + top-3 ----------------
__global__ __launch_bounds__(128) void ksim(const double* __restrict__ xt, int* __restrict__ idxg)
{
  __shared__ double sx[NBAR*CCH];
  __shared__ double simL[NBAR*NBAR];
  const int g = blockIdx.x;             // t*BATCH + b
  const int tid = threadIdx.x;
  const double* base = xt + (size_t)g*NBAR*CCH;
  for (int e = tid; e < NBAR*CCH; e += 128) sx[e] = base[e];
  __syncthreads();
  for (int p = tid; p < NBAR*NBAR; p += 128) {
    const int n = p / NBAR, m = p - n*NBAR;
    double acc = 0.0;
    #pragma unroll
    for (int c = 0; c < CCH; ++c) acc += sx[n*CCH+c]*sx[m*CCH+c];
    simL[p] = acc;
  }
  __syncthreads();
  if (tid < NBAR) {
    const double* row = simL + tid*NBAR;
    double v0=-1e300, v1=-1e300, v2=-1e300; int i0=0, i1=0, i2=0;
    for (int m = 0; m < NBAR; ++m) {
      const double v = row[m];
      if      (v > v0) { v2=v1;i2=i1; v1=v0;i1=i0; v0=v;i0=m; }
      else if (v > v1) { v2=v1;i2=i1; v1=v; i1=m; }
      else if (v > v2) { v2=v; i2=m; }
    }
    int* op = idxg + (g*NBAR + tid)*3;
    op[0]=i0; op[1]=i1; op[2]=i2;
  }
}

// ---------------- drive precompute ----------------
__global__ __launch_bounds__(256) void kdrive(const double* __restrict__ xt,
    const float* __restrict__ th_w, const double* __restrict__ cbias,
    double* __restrict__ drive, int c0)
{
  __shared__ float  sw[32*65];
  __shared__ double sx8[8*CCH];
  const int bx = blockIdx.x;            // i*NBAR + n
  const int i = bx / NBAR, n = bx % NBAR;
  const int tid = threadIdx.x;
  const int o = tid & 31, rq = tid >> 5;
  for (int e = tid; e < 2048; e += 256) sw[(e>>6)*65 + (e&63)] = th_w[bx*2048 + e];
  const double cb = cbias[i*NEUR + n*PSZ + o];
  __syncthreads();
  for (int base = 0; base < TCH*BATCH; base += 8) {
    for (int e = tid; e < 512; e += 256) {
      const int rr = e >> 6, cc = e & 63;
      const int row = base + rr, tloc = row >> 6, bb = row & 63;
      sx8[e] = xt[(((c0+tloc)*BATCH + bb)*NBAR + n)*CCH + cc];
    }
    __syncthreads();
    double acc = cb;
    #pragma unroll
    for (int c = 0; c < CCH; ++c) acc += sx8[rq*CCH + c] * (double)sw[o*65 + c];
    drive[((base+rq)*NPOPS + i)*NEUR + n*PSZ + o] = acc;
    __syncthreads();
  }
}

// scatter source-J spikes (masks g0,g1 for barrels n0,n1) into acc registers
template<int J>
__device__ __forceinline__ void gatherJ(unsigned g0, unsigned g1, int n0, int n1v,
    const float* __restrict__ gw, int o, double* a0, double* a1)
{
  constexpr int NT = G_NT[J];
  const float* base = gw + G_OFFW[J] + o;
  while (g0 | g1) {
    const int fA = g0 ? n0*32  + (__ffs(g0)-1) : 1248;  g0 &= g0-1;
    const int fB = g0 ? n0*32  + (__ffs(g0)-1) : 1248;  g0 &= g0-1;
    const int fC = g1 ? n1v*32 + (__ffs(g1)-1) : 1248;  g1 &= g1-1;
    const int fD = g1 ? n1v*32 + (__ffs(g1)-1) : 1248;  g1 &= g1-1;
    const float* pA = base + fA*(NT*32);
    const float* pB = base + fB*(NT*32);
    const float* pC = base + fC*(NT*32);
    const float* pD = base + fD*(NT*32);
    float wA[NT], wB[NT], wC[NT], wD[NT];
    #pragma unroll
    for (int tt = 0; tt < NT; ++tt) { wA[tt]=pA[tt*32]; wB[tt]=pB[tt*32];
                                      wC[tt]=pC[tt*32]; wD[tt]=pD[tt*32]; }
    #pragma unroll
    for (int tt = 0; tt < NT; ++tt) {
      constexpr int CU = G_CUM[J];
      const int tg = G_TGT[CU+tt];
      a0[tg] += (double)wA[tt]; a0[tg] += (double)wB[tt];
      a1[tg] += (double)wC[tt]; a1[tg] += (double)wD[tt];
    }
  }
}

// ---------------- recurrent core: 640 thr (20 half-wave slots x <=2 barrels) ----------------
__global__ __launch_bounds__(640) void krec(
    const double* __restrict__ drv, const int* __restrict__ idxg,
    const float* __restrict__ gw, const float* __restrict__ aggTg,
    const float* __restrict__ agg_b, const double* __restrict__ alro,
    double* __restrict__ memG, double* __restrict__ bbrG,
    double* __restrict__ accG, double* __restrict__ stProj, unsigned* __restrict__ stSp,
    float* __restrict__ hOut, float* __restrict__ mOut, int t0)
{
  __shared__ double   proj[NBAR*PSZ];   //  9,984 B
  __shared__ float    aggT[256*PSZ];    // 32,768 B
  __shared__ unsigned spM[NPOPS*40];    //  1,280 B
  const int b = blockIdx.x, tid = threadIdx.x;
  const int o = tid & 31, s = tid >> 5;
  const int n0 = s, n1 = s + 20;
  const bool h1 = (n1 < NBAR);          // s < 19
  const int n1v = h1 ? n1 : n0;

  for (int e = tid; e < 256*PSZ; e += 640) aggT[e] = aggTg[e];

  double acc0[NPOPS], acc1[NPOPS];
  const size_t mbase = (size_t)b*NPOPS*NEUR;
  if (t0 == 0) {
    #pragma unroll
    for (int i = 0; i < NPOPS; ++i) {
      acc0[i]=0.0; acc1[i]=0.0;
      memG[mbase + i*NEUR + n0*PSZ + o] = 0.0;
      bbrG[mbase + i*NEUR + n0*PSZ + o] = 0.0;
      if (h1) { memG[mbase + i*NEUR + n1*PSZ + o] = 0.0;
                bbrG[mbase + i*NEUR + n1*PSZ + o] = 0.0; }
    }
    for (int e = tid; e < NBAR*PSZ; e += 640) proj[e] = 0.0;
    for (int e = tid; e < NPOPS*40; e += 640) spM[e] = 0u;
  } else {
    #pragma unroll
    for (int i = 0; i < NPOPS; ++i) {
      acc0[i] = accG[mbase + i*NEUR + n0*PSZ + o];
      acc1[i] = h1 ? accG[mbase + i*NEUR + n1*PSZ + o] : 0.0;
    }
    for (int e = tid; e < NBAR*PSZ; e += 640) proj[e] = stProj[b*NEUR + e];
    for (int e = tid; e < NPOPS*40; e += 640)
      spM[e] = ((e % 40) < NBAR) ? stSp[b*NPOPS*NBAR + (e/40)*NBAR + (e%40)] : 0u;
  }
  __syncthreads();
  const double aggBo = (double)agg_b[o];

  #pragma unroll 1
  for (int tt = 0; tt < TCH; ++tt) {
    const int t = t0 + tt;
    const double* drvT = drv + ((size_t)(tt*BATCH + b))*NPOPS*NEUR;
    #pragma unroll
    for (int i = 0; i < NPOPS; ++i) {
      acc0[i] += drvT[i*NEUR + n0*PSZ + o];
      if (h1) acc1[i] += drvT[i*NEUR + n1*PSZ + o];
    }
    int ia0[3], ia1[3];
    { const int* ip = idxg + ((t*BATCH+b)*NBAR + n0)*3; ia0[0]=ip[0]; ia0[1]=ip[1]; ia0[2]=ip[2]; }
    if (h1) { const int* ip = idxg + ((t*BATCH+b)*NBAR + n1)*3; ia1[0]=ip[0]; ia1[1]=ip[1]; ia1[2]=ip[2]; }
    else    { ia1[0]=ia1[1]=ia1[2]=0; }

    #pragma unroll
    for (int i = 0; i < NPOPS; ++i) {
      // ---- phase 1: issue state loads, fold acc + neighbor agg
      const int eA = i*NEUR + n0*PSZ + o;
      const int eB = i*NEUR + n1v*PSZ + o;
      const double al0 = alro[2*eA], ro0 = alro[2*eA+1];
      const double al1 = alro[2*eB], ro1 = alro[2*eB+1];
      const double mv0 = memG[mbase+eA], bv0 = bbrG[mbase+eA];
      const double mv1 = memG[mbase+eB], bv1 = bbrG[mbase+eB];
      double cur0 = acc0[i]; acc0[i] = 0.0;
      double cur1 = acc1[i]; acc1[i] = 0.0;
      if (t > 0) {
        cur0 += 0.1*((proj[ia0[0]*PSZ+o]+proj[ia0[1]*PSZ+o]+proj[ia0[2]*PSZ+o])/3.0 + aggBo);
        if (h1)
          cur1 += 0.1*((proj[ia1[0]*PSZ+o]+proj[ia1[1]*PSZ+o]+proj[ia1[2]*PSZ+o])/3.0 + aggBo);
      }
      __syncthreads();   // A: proj reads done before any proj write

      // ---- phase 2: neuron update, ballot, outputs, proj delta
      unsigned newM0, newM1;
      {
        const unsigned oldM = spM[i*40 + n0];
        const double sOld = (double)((oldM >> o) & 1u);
        const double bn  = ro0*bv0 + (1.0-ro0)*sOld;
        const double Bth = 0.02 + 1.8*bn;
        const double mN  = mv0*al0 + (1.0-al0)*cur0;
        const int spk = (mN - Bth) > 0.0;
        memG[mbase+eA] = mN - Bth*(double)spk;
        bbrG[mbase+eA] = bn;
        const int ob = ((b*TSTEPS + t)*NBAR + n0)*256 + i*PSZ + o;
        hOut[ob] = (float)spk;
        mOut[ob] = (float)mN;
        const unsigned long long bal = __ballot(spk);
        newM0 = (tid & 32) ? (unsigned)(bal >> 32) : (unsigned)(bal & 0xffffffffULL);
        if (o == 0) spM[i*40 + n0] = newM0;
        unsigned diff = newM0 ^ oldM;
        double pv = proj[n0*PSZ + o];
        while (diff) {
          unsigned d = diff;
          const int cA = __ffs(d)-1; d &= d-1;
          const bool hB = d!=0; const int cB = hB ? __ffs(d)-1 : cA; d &= d-1;
          const bool hC = d!=0; const int cC = hC ? __ffs(d)-1 : cA; d &= d-1;
          const bool hD = d!=0; const int cD = hD ? __ffs(d)-1 : cA; d &= d-1;
          diff = d;
          const double wA = (double)aggT[(i*PSZ+cA)*PSZ+o];
          const double wB = (double)aggT[(i*PSZ+cB)*PSZ+o];
          const double wC = (double)aggT[(i*PSZ+cC)*PSZ+o];
          const double wD = (double)aggT[(i*PSZ+cD)*PSZ+o];
          pv += ((newM0>>cA)&1u) ? wA : -wA;
          pv += hB ? (((newM0>>cB)&1u) ? wB : -wB) : 0.0;
          pv += hC ? (((newM0>>cC)&1u) ? wC : -wC) : 0.0;
          pv += hD ? (((newM0>>cD)&1u) ? wD : -wD) : 0.0;
        }
        proj[n0*PSZ + o] = pv;
      }
      {
        const unsigned oldM = h1 ? spM[i*40 + n1] : 0u;
        const double sOld = (double)((oldM >> o) & 1u);
        const double bn  = ro1*bv1 + (1.0-ro1)*sOld;
        const double Bth = 0.02 + 1.8*bn;
        const double mN  = mv1*al1 + (1.0-al1)*cur1;
        const int spk = (mN - Bth) > 0.0;
        if (h1) {
          memG[mbase+eB] = mN - Bth*(double)spk;
          bbrG[mbase+eB] = bn;
          const int ob = ((b*TSTEPS + t)*NBAR + n1)*256 + i*PSZ + o;
          hOut[ob] = (float)spk;
          mOut[ob] = (float)mN;
        }
        const unsigned long long bal = __ballot(h1 && spk);
        newM1 = (tid & 32) ? (unsigned)(bal >> 32) : (unsigned)(bal & 0xffffffffULL);
        if (h1) {
          if (o == 0) spM[i*40 + n1] = newM1;
          unsigned diff = newM1 ^ oldM;
          double pv = proj[n1*PSZ + o];
          while (diff) {
            unsigned d = diff;
            const int cA = __ffs(d)-1; d &= d-1;
            const bool hB = d!=0; const int cB = hB ? __ffs(d)-1 : cA; d &= d-1;
            const bool hC = d!=0; const int cC = hC ? __ffs(d)-1 : cA; d &= d-1;
            const bool hD = d!=0; const int cD = hD ? __ffs(d)-1 : cA; d &= d-1;
            diff = d;
            const double wA = (double)aggT[(i*PSZ+cA)*PSZ+o];
            const double wB = (double)aggT[(i*PSZ+cB)*PSZ+o];
            const double wC = (double)aggT[(i*PSZ+cC)*PSZ+o];
            const double wD = (double)aggT[(i*PSZ+cD)*PSZ+o];
            pv += ((newM1>>cA)&1u) ? wA : -wA;
            pv += hB ? (((newM1>>cB)&1u) ? wB : -wB) : 0.0;
            pv += hC ? (((newM1>>cC)&1u) ? wC : -wC) : 0.0;
            pv += hD ? (((newM1>>cD)&1u) ? wD : -wD) : 0.0;
          }
          proj[n1*PSZ + o] = pv;
        }
      }
      __syncthreads();   // B: proj writes visible before next pop's reads

      // ---- scatter source-i spikes into acc regs (overlaps next phase 1)
      const unsigned g0 = newM0, g1 = h1 ? newM1 : 0u;
      if      (i == 0) gatherJ<0>(g0, g1, n0, n1v, gw, o, acc0, acc1);
      else if (i == 1) gatherJ<1>(g0, g1, n0, n1v, gw, o, acc0, acc1);
      else if (i == 2) gatherJ<2>(g0, g1, n0, n1v, gw, o, acc0, acc1);
      else if (i == 3) gatherJ<3>(g0, g1, n0, n1v, gw, o, acc0, acc1);
      else if (i == 4) gatherJ<4>(g0, g1, n0, n1v, gw, o, acc0, acc1);
      else if (i == 5) gatherJ<5>(g0, g1, n0, n1v, gw, o, acc0, acc1);
      else if (i == 6) gatherJ<6>(g0, g1, n0, n1v, gw, o, acc0, acc1);
      else             gatherJ<7>(g0, g1, n0, n1v, gw, o, acc0, acc1);
    }
  }

  // persist chunk state
  #pragma unroll
  for (int i = 0; i < NPOPS; ++i) {
    accG[mbase + i*NEUR + n0*PSZ + o] = acc0[i];
    if (h1) accG[mbase + i*NEUR + n1*PSZ + o] = acc1[i];
  }
  for (int e = tid; e < NEUR; e += 640) stProj[b*NEUR + e] = proj[e];
  for (int e = tid; e < NPOPS*NBAR; e += 640) stSp[b*NPOPS*NBAR + e] = spM[(e/NBAR)*40 + (e%NBAR)];
}

// ---------------- readout ----------------
__global__ __launch_bounds__(256) void kread(const float* __restrict__ hBase,
    const float* __restrict__ ro_w, const float* __restrict__ ro_b, float* __restrict__ outp)
{
  __shared__ double part[2][128];
  __shared__ double meanv[128];
  __shared__ double lg[36];
  const int b = blockIdx.x, tid = threadIdx.x;
  const int d = tid & 127, half = tid >> 7;
  double acc = 0.0;
  for (int r = half*1248; r < half*1248 + 1248; ++r)
    acc += (double)hBase[((size_t)b*2496 + r)*256 + 128 + d];
  part[half][d] = acc;
  __syncthreads();
  if (tid < 128) meanv[tid] = (part[0][tid] + part[1][tid]) / 2496.0;
  __syncthreads();
  if (tid < 36) {
    double a = (double)ro_b[tid];
    for (int e = 0; e < 128; ++e) a += meanv[e]*(double)ro_w[tid*128 + e];
    lg[tid] = a;
  }
  __syncthreads();
  if (tid == 0) {
    double mx = lg[0];
    for (int dd = 1; dd < 36; ++dd) mx = fmax(mx, lg[dd]);
    double ex[36]; double sum = 0.0;
    for (int dd = 0; dd < 36; ++dd) { ex[dd] = exp(lg[dd]-mx); sum += ex[dd]; }
    for (int dd = 0; dd < 36; ++dd) outp[b*36 + dd] = (float)(ex[dd]/sum);
  }
}

// ---------------- launcher ----------------
extern "C" void kernel_launch(void* const* d_in, const int* in_sizes, int n_in,
                              void* d_out, int out_size, void* d_ws, size_t ws_size,
                              hipStream_t stream)
{
  const float* inp     = (const float*)d_in[0];
  const float* comp_w  = (const float*)d_in[1];
  const float* comp_b  = (const float*)d_in[2];
  const float* th_w    = (const float*)d_in[3];
  const float* th_b    = (const float*)d_in[4];
  const float* pop_w   = (const float*)d_in[5];
  const float* pop_b   = (const float*)d_in[6];
  const float* tau_adp = (const float*)d_in[7];
  const float* tau_m   = (const float*)d_in[8];
  const float* agg_w   = (const float*)d_in[9];
  const float* agg_b   = (const float*)d_in[10];
  const float* ro_w    = (const float*)d_in[11];
  const float* ro_b    = (const float*)d_in[12];

  char* ws = (char*)d_ws;
  double*   xt     = (double*)  (ws + OFS_XT);
  double*   drive  = (double*)  (ws + OFS_DRIVE);
  int*      idxg   = (int*)     (ws + OFS_IDX);
  float*    gw     = (float*)   (ws + OFS_GW);
  float*    aggT   = (float*)   (ws + OFS_AGGT);
  double*   cbias  = (double*)  (ws + OFS_CBIAS);
  double*   alro   = (double*)  (ws + OFS_ALRO);
  double*   memG   = (double*)  (ws + OFS_MEMG);
  double*   bbrG   = (double*)  (ws + OFS_BBRG);
  double*   accG   = (double*)  (ws + OFS_ACCG);
  double*   stProj = (double*)  (ws + OFS_STPROJ);
  unsigned* stSp   = (unsigned*)(ws + OFS_STSP);

  float* outp = (float*)d_out;                 // (64,36) softmax
  float* hOut = outp + 64*36;                  // (64,64,39,256)
  float* mOut = hOut + 64*64*39*256;           // (64,64,39,256)

  kconv <<<BATCH*NBAR, 256, 0, stream>>>(inp, comp_w, comp_b, xt);
  kprepw<<<NPOPS*NBAR, 256, 0, stream>>>(pop_w, gw);
  kprepn<<<39, 256, 0, stream>>>(th_b, pop_b, tau_adp, tau_m, agg_w, cbias, alro, aggT);
  ksim  <<<TSTEPS*BATCH, 128, 0, stream>>>(xt, idxg);
  for (int c0 = 0; c0 < TSTEPS; c0 += TCH) {
    kdrive<<<NPOPS*NBAR, 256, 0, stream>>>(xt, th_w, cbias, drive, c0);
    krec  <<<BATCH, 640, 0, stream>>>(drive, idxg, gw, aggT, agg_b, alro,
                                      memG, bbrG, accG, stProj, stSp, hOut, mOut, c0);
  }
  kread <<<BATCH, 256, 0, stream>>>(hOut, ro_w, ro_b, outp);
}

// Round 4
// 3485.685 us; speedup vs baseline: 2.1223x; 1.3002x over previous
//
#include <hip/hip_runtime.h>
#include <math.h>

// ---------------- problem constants ----------------
#define NBAR   39
#define NPOPS  8
#define PSZ    32
#define TSTEPS 64
#define BATCH  64
#define CCH    64
#define NEUR   (NBAR*PSZ)      // 1248
#define NCONNS 37
#define TCH    8               // time chunk (8 chunks of 8)

// connectivity
constexpr int C_NSRC[NPOPS] = {5,5,6,6,4,3,6,2};
constexpr int C_OFF [NPOPS] = {0,5,10,16,22,26,29,35};

// source-grouped tables: for source pop j, its target pops (ascending) and the
// connection index k supplying weights pop_w[k] for (source j -> target i).
constexpr int G_NT  [NPOPS] = {3,5,5,5,4,4,5,6};
constexpr int G_CUM [NPOPS] = {0,3,8,13,18,22,26,31};
constexpr int G_TGT [NCONNS] = {0,1,4,  0,1,2,3,5,  0,1,2,3,6,  0,1,2,3,6,
                                0,1,4,6,  2,3,5,6,  2,3,4,6,7,  2,3,4,5,6,7};
constexpr int G_K   [NCONNS] = {0,5,22, 1,6,10,16,26, 2,7,11,17,29, 3,8,12,18,30,
                                4,9,23,31, 13,19,27,32, 14,20,24,33,35, 15,21,25,28,34,36};
// region j: 1249 flat (n*32+c) slots (incl. zero-pad slot 1248) x NT x 32 floats
constexpr int G_OFFW[NPOPS] = {0,119904,319744,519584,719424,879296,1039168,1239008};

// ---------------- workspace layout (bytes) ----------------
#define OFS_XT     0           // f64 [T][B][NBAR][CCH]        81,788,928
#define OFS_DRIVE  81788928    // f64 [TCH][B][NPOPS][NEUR]    40,894,464
#define OFS_IDX    122683392   // i32 [T][B][NBAR][3]           1,916,928
#define OFS_GW     124600320   // f32 grouped weights           5,915,264
#define OFS_AGGT   130515584   // f32 [256][32]                    32,768
#define OFS_CBIAS  130548352   // f64 [NPOPS][NEUR]                79,872
#define OFS_ALRO   130628224   // f64 [NPOPS*NEUR][2]             159,744
#define OFS_MEMG   130787968   // f64 [B][NPOPS][NEUR]          5,111,808
#define OFS_BBRG   135899776   // f64 same                      5,111,808
#define OFS_ACCG   141011584   // f64 same                      5,111,808
#define OFS_STPROJ 146123392   // f64 [B][NEUR]                   638,976
#define OFS_STSP   146762368   // u32 [B][NPOPS][NBAR]             79,872
// end ~146.8 MB

// raw barrier: order LDS hand-off only; do NOT drain vmem (scatter loads /
// output stores have register-only / no consumers across the barrier).
#define STEP_BAR() do { asm volatile("s_waitcnt lgkmcnt(0)" ::: "memory"); \
  __builtin_amdgcn_s_barrier(); asm volatile("" ::: "memory"); } while(0)

// ---------------- conv1d(2->64,k=3,s=2,p=1) -> xt f64 ----------------
__global__ __launch_bounds__(256) void kconv(const float* __restrict__ inp,
    const float* __restrict__ comp_w, const float* __restrict__ comp_b,
    double* __restrict__ xt)
{
  __shared__ float si[256];
  const int bn = blockIdx.x;
  const int b = bn / NBAR, n = bn % NBAR;
  const int tid = threadIdx.x;
  si[tid] = inp[bn*256 + tid];
  __syncthreads();
  const int c = tid & 63, tq = tid >> 6;
  double wv[6];
  #pragma unroll
  for (int u = 0; u < 6; ++u) wv[u] = (double)comp_w[c*6 + u];
  const double cb = (double)comp_b[c];
  for (int t = tq; t < TSTEPS; t += 4) {
    const int p0 = 2*t - 1;
    double acc = cb;
    if (p0 >= 0) acc += (double)si[p0]     * wv[0];
    acc             += (double)si[p0+1]    * wv[1];
    acc             += (double)si[p0+2]    * wv[2];
    if (p0 >= 0) acc += (double)si[128+p0] * wv[3];
    acc             += (double)si[128+p0+1]* wv[4];
    acc             += (double)si[128+p0+2]* wv[5];
    xt[((t*BATCH + b)*NBAR + n)*CCH + c] = acc;
  }
}

// ---------------- grouped-weight build ----------------
__global__ __launch_bounds__(256) void kprepw(const float* __restrict__ pop_w,
    float* __restrict__ gw)
{
  const int bx = blockIdx.x;          // j*NBAR + n
  const int j = bx / NBAR, n = bx % NBAR;
  const int NT = G_NT[j];
  const int total = NT*1024;
  for (int e = threadIdx.x; e < total; e += 256) {
    const int c = e / (NT*32), r = e % (NT*32), tt = r >> 5, oo = r & 31;
    const int k = G_K[G_CUM[j]+tt];
    gw[G_OFFW[j] + (n*32+c)*NT*32 + tt*32 + oo] = pop_w[k*39936 + n*1024 + oo*32 + c];
  }
  if (n == 0)
    for (int e = threadIdx.x; e < NT*32; e += 256)
      gw[G_OFFW[j] + 1248*NT*32 + e] = 0.0f;   // zero-pad flat slot
}

// ---------------- per-neuron constants + aggT transpose ----------------
__global__ __launch_bounds__(256) void kprepn(const float* __restrict__ th_b,
    const float* __restrict__ pop_b, const float* __restrict__ tau_adp,
    const float* __restrict__ tau_m, const float* __restrict__ agg_w,
    double* __restrict__ cbias, double* __restrict__ alro, float* __restrict__ aggT)
{
  const int e = blockIdx.x*256 + threadIdx.x;
  if (e < 8192) aggT[e] = agg_w[(e & 31)*256 + (e >> 5)];   // [m][o] <- [o][m]
  if (e >= NPOPS*NEUR) return;
  const int i = e / NEUR, r = e % NEUR;
  double cb = (double)th_b[e];
  const int no = C_NSRC[i], ofi = C_OFF[i];
  for (int jj = 0; jj < no; ++jj) cb += (double)pop_b[(ofi+jj)*NEUR + r];
  cbias[e] = cb;
  alro[2*e]   = exp(-1.0/(double)tau_m[e]);
  alro[2*e+1] = exp(-1.0/(double)tau_adp[e]);
}

// ---------------- similarity + top-3 ----------------
__global__ __launch_bounds__(128) void ksim(const double* __restrict__ xt, int* __restrict__ idxg)
{
  __shared__ double sx[NBAR*CCH];
  __shared__ double simL[NBAR*NBAR];
  const int g = blockIdx.x;             // t*BATCH + b
  const int tid = threadIdx.x;
  const double* base = xt + (size_t)g*NBAR*CCH;
  for (int e = tid; e < NBAR*CCH; e += 128) sx[e] = base[e];
  __syncthreads();
  for (int p = tid; p < NBAR*NBAR; p += 128) {
    const int n = p / NBAR, m = p - n*NBAR;
    double acc = 0.0;
    #pragma unroll
    for (int c = 0; c < CCH; ++c) acc += sx[n*CCH+c]*sx[m*CCH+c];
    simL[p] = acc;
  }
  __syncthreads();
  if (tid < NBAR) {
    const double* row = simL + tid*NBAR;
    double v0=-1e300, v1=-1e300, v2=-1e300; int i0=0, i1=0, i2=0;
    for (int m = 0; m < NBAR; ++m) {
      const double v = row[m];
      if      (v > v0) { v2=v1;i2=i1; v1=v0;i1=i0; v0=v;i0=m; }
      else if (v > v1) { v2=v1;i2=i1; v1=v; i1=m; }
      else if (v > v2) { v2=v; i2=m; }
    }
    int* op = idxg + (g*NBAR + tid)*3;
    op[0]=i0; op[1]=i1; op[2]=i2;
  }
}

// ---------------- drive precompute: register-tiled GEMM per barrel ----------------
// grid: NBAR * 8 slices; block 512. Thread (ot, rt): 4 rows x 8 pops for col ot.
__global__ __launch_bounds__(512) void kdrive(const double* __restrict__ xt,
    const float* __restrict__ th_w, const double* __restrict__ cbias,
    double* __restrict__ drive, int c0)
{
  __shared__ double sx[64*64];          // [row][c]   32 KB
  __shared__ float  sw[64*256];         // [c][pop*32+o]  64 KB
  const int n = blockIdx.x % NBAR, sl = blockIdx.x / NBAR;
  const int tid = threadIdx.x;
  for (int e = tid; e < 64*256; e += 512) {
    const int f = e >> 6, c = e & 63;   // f = pop*32+o
    sw[c*256 + f] = th_w[((f>>5)*NBAR + n)*2048 + (f&31)*64 + c];
  }
  for (int e = tid; e < 64*64; e += 512) {
    const int rr = e >> 6, cc = e & 63;
    const int g = sl*64 + rr, tt = g >> 6, bb = g & 63;
    sx[e] = xt[(((size_t)(c0+tt)*BATCH + bb)*NBAR + n)*CCH + cc];
  }
  __syncthreads();
  const int ot = tid & 31, rt = tid >> 5;   // rt in [0,16): rows rt*4..+3
  double acc[4][8];
  #pragma unroll
  for (int k = 0; k < 8; ++k) {
    const double cb = cbias[k*NEUR + n*PSZ + ot];
    #pragma unroll
    for (int j = 0; j < 4; ++j) acc[j][k] = cb;
  }
  #pragma unroll 1
  for (int c = 0; c < 64; ++c) {
    double xv[4];
    #pragma unroll
    for (int j = 0; j < 4; ++j) xv[j] = sx[(rt*4+j)*64 + c];
    float wv[8];
    #pragma unroll
    for (int k = 0; k < 8; ++k) wv[k] = sw[c*256 + k*32 + ot];
    #pragma unroll
    for (int j = 0; j < 4; ++j)
      #pragma unroll
      for (int k = 0; k < 8; ++k)
        acc[j][k] += xv[j] * (double)wv[k];
  }
  #pragma unroll
  for (int j = 0; j < 4; ++j)
    #pragma unroll
    for (int k = 0; k < 8; ++k)
      drive[((size_t)(sl*64 + rt*4 + j)*NPOPS + k)*NEUR + n*PSZ + ot] = acc[j][k];
}

// scatter source-J spikes (masks g0,g1) into acc registers, 4+4 bits per wait
template<int J>
__device__ __forceinline__ void scatJ(unsigned g0, unsigned g1, int n0, int n1v,
    const float* __restrict__ gw, int o, double* __restrict__ a0, double* __restrict__ a1)
{
  constexpr int NT = G_NT[J];
  constexpr int CU = G_CUM[J];
  const float* base = gw + G_OFFW[J] + o;
  while (g0 | g1) {
    int f0[4], f1[4];
    #pragma unroll
    for (int u = 0; u < 4; ++u) {
      f0[u] = g0 ? (n0*32  + (__ffs(g0)-1)) : 1248; g0 &= g0-1;
      f1[u] = g1 ? (n1v*32 + (__ffs(g1)-1)) : 1248; g1 &= g1-1;
    }
    float w0[4][NT], w1[4][NT];
    #pragma unroll
    for (int u = 0; u < 4; ++u) {
      const float* p0 = base + (size_t)f0[u]*(NT*32);
      const float* p1 = base + (size_t)f1[u]*(NT*32);
      #pragma unroll
      for (int tt = 0; tt < NT; ++tt) { w0[u][tt]=p0[tt*32]; w1[u][tt]=p1[tt*32]; }
    }
    #pragma unroll
    for (int tt = 0; tt < NT; ++tt) {
      const int tg = G_TGT[CU+tt];
      a0[tg] += (((double)w0[0][tt]+(double)w0[1][tt]) + ((double)w0[2][tt]+(double)w0[3][tt]));
      a1[tg] += (((double)w1[0][tt]+(double)w1[1][tt]) + ((double)w1[2][tt]+(double)w1[3][tt]));
    }
  }
}

// ---------------- recurrent core: 640 thr, 1 raw barrier per pop-step ----------------
__global__ __launch_bounds__(640) void krec(
    const double* __restrict__ drv, const int* __restrict__ idxg,
    const float* __restrict__ gw, const float* __restrict__ aggTg,
    const float* __restrict__ agg_b, const double* __restrict__ alro,
    double* __restrict__ memG, double* __restrict__ bbrG,
    double* __restrict__ accG, double* __restrict__ stProj, unsigned* __restrict__ stSp,
    float* __restrict__ hOut, float* __restrict__ mOut, int t0)
{
  __shared__ double   proj[2][NBAR*PSZ];  // 19,968 B ping-pong
  __shared__ float    aggT[256*PSZ];      // 32,768 B
  __shared__ unsigned spM[NPOPS*40];      //  1,280 B
  const int b = blockIdx.x, tid = threadIdx.x;
  const int o = tid & 31, s = tid >> 5;   // 20 half-wave slots
  const int n0 = s, n1 = s + 20;
  const bool h1 = (n1 < NBAR);            // s < 19
  const int n1v = h1 ? n1 : n0;

  for (int e = tid; e < 256*PSZ; e += 640) aggT[e] = aggTg[e];

  double mem0[NPOPS], mem1[NPOPS], bbr0[NPOPS], bbr1[NPOPS], acc0[NPOPS], acc1[NPOPS];
  const size_t mbase = (size_t)b*NPOPS*NEUR;
  if (t0 == 0) {
    #pragma unroll
    for (int i = 0; i < NPOPS; ++i) {
      mem0[i]=0.0; mem1[i]=0.0; bbr0[i]=0.0; bbr1[i]=0.0; acc0[i]=0.0; acc1[i]=0.0;
    }
    for (int e = tid; e < NBAR*PSZ; e += 640) proj[0][e] = 0.0;
    for (int e = tid; e < NPOPS*40; e += 640) spM[e] = 0u;
  } else {
    #pragma unroll
    for (int i = 0; i < NPOPS; ++i) {
      const size_t eA = mbase + i*NEUR + n0*PSZ + o;
      const size_t eB = mbase + i*NEUR + n1v*PSZ + o;
      mem0[i] = memG[eA]; bbr0[i] = bbrG[eA]; acc0[i] = accG[eA];
      mem1[i] = h1 ? memG[eB] : 0.0;
      bbr1[i] = h1 ? bbrG[eB] : 0.0;
      acc1[i] = h1 ? accG[eB] : 0.0;
    }
    for (int e = tid; e < NBAR*PSZ; e += 640) proj[0][e] = stProj[b*NEUR + e];
    for (int e = tid; e < NPOPS*40; e += 640)
      spM[e] = ((e % 40) < NBAR) ? stSp[b*NPOPS*NBAR + (e/40)*NBAR + (e%40)] : 0u;
  }
  __syncthreads();
  const double aggBo = (double)agg_b[o];
  int rb = 0;

  #pragma unroll 1
  for (int tt = 0; tt < TCH; ++tt) {
    const int t = t0 + tt;
    const double* drvT = drv + ((size_t)(tt*BATCH + b))*NPOPS*NEUR;
    #pragma unroll
    for (int i = 0; i < NPOPS; ++i) {
      acc0[i] += drvT[i*NEUR + n0*PSZ + o];
      if (h1) acc1[i] += drvT[i*NEUR + n1*PSZ + o];
    }
    int ia0[3], ia1[3];
    { const int* ip = idxg + ((t*BATCH+b)*NBAR + n0)*3; ia0[0]=ip[0]; ia0[1]=ip[1]; ia0[2]=ip[2]; }
    if (h1) { const int* ip = idxg + ((t*BATCH+b)*NBAR + n1)*3; ia1[0]=ip[0]; ia1[1]=ip[1]; ia1[2]=ip[2]; }
    else    { ia1[0]=ia1[1]=ia1[2]=0; }

    #pragma unroll
    for (int i = 0; i < NPOPS; ++i) {
      const int eA = i*NEUR + n0*PSZ + o;
      const int eB = i*NEUR + n1v*PSZ + o;
      const double al0 = alro[2*eA], ro0 = alro[2*eA+1];
      const double al1 = alro[2*eB], ro1 = alro[2*eB+1];
      const double* prj = proj[rb];
      double*       prw = proj[rb^1];

      // ---- phase 1: fold acc + neighbor agg (reads prj)
      double cur0 = acc0[i]; acc0[i] = 0.0;
      double cur1 = acc1[i]; acc1[i] = 0.0;
      if (t > 0) {
        cur0 += 0.1*((prj[ia0[0]*PSZ+o]+prj[ia0[1]*PSZ+o]+prj[ia0[2]*PSZ+o])/3.0 + aggBo);
        if (h1)
          cur1 += 0.1*((prj[ia1[0]*PSZ+o]+prj[ia1[1]*PSZ+o]+prj[ia1[2]*PSZ+o])/3.0 + aggBo);
      }

      // ---- phase 2: neuron update, ballot, outputs, proj copy+delta (writes prw)
      unsigned newM0, newM1;
      {
        const unsigned oldM = spM[i*40 + n0];
        const double sOld = (double)((oldM >> o) & 1u);
        const double bn  = ro0*bbr0[i] + (1.0-ro0)*sOld;
        const double Bth = 0.02 + 1.8*bn;
        const double mN  = mem0[i]*al0 + (1.0-al0)*cur0;
        const int spk = (mN - Bth) > 0.0;
        mem0[i] = mN - Bth*(double)spk;
        bbr0[i] = bn;
        const int ob = ((b*TSTEPS + t)*NBAR + n0)*256 + i*PSZ + o;
        hOut[ob] = (float)spk;
        mOut[ob] = (float)mN;
        const unsigned long long bal = __ballot(spk);
        newM0 = (tid & 32) ? (unsigned)(bal >> 32) : (unsigned)(bal & 0xffffffffULL);
        if (o == 0) spM[i*40 + n0] = newM0;
        unsigned diff = newM0 ^ oldM;
        double pv = prj[n0*PSZ + o];
        while (diff) {
          unsigned d = diff;
          const int cA = __ffs(d)-1; d &= d-1;
          const bool hB = d!=0; const int cB = hB ? __ffs(d)-1 : cA; d &= d-1;
          const bool hC = d!=0; const int cC = hC ? __ffs(d)-1 : cA; d &= d-1;
          const bool hD = d!=0; const int cD = hD ? __ffs(d)-1 : cA; d &= d-1;
          diff = d;
          const double wA = (double)aggT[(i*PSZ+cA)*PSZ+o];
          const double wB = (double)aggT[(i*PSZ+cB)*PSZ+o];
          const double wC = (double)aggT[(i*PSZ+cC)*PSZ+o];
          const double wD = (double)aggT[(i*PSZ+cD)*PSZ+o];
          pv += ((newM0>>cA)&1u) ? wA : -wA;
          pv += hB ? (((newM0>>cB)&1u) ? wB : -wB) : 0.0;
          pv += hC ? (((newM0>>cC)&1u) ? wC : -wC) : 0.0;
          pv += hD ? (((newM0>>cD)&1u) ? wD : -wD) : 0.0;
        }
        prw[n0*PSZ + o] = pv;
      }
      {
        const unsigned oldM = h1 ? spM[i*40 + n1] : 0u;
        const double sOld = (double)((oldM >> o) & 1u);
        const double bn  = ro1*bbr1[i] + (1.0-ro1)*sOld;
        const double Bth = 0.02 + 1.8*bn;
        const double mN  = mem1[i]*al1 + (1.0-al1)*cur1;
        const int spk = (mN - Bth) > 0.0;
        mem1[i] = mN - Bth*(double)spk;
        bbr1[i] = bn;
        if (h1) {
          const int ob = ((b*TSTEPS + t)*NBAR + n1)*256 + i*PSZ + o;
          hOut[ob] = (float)spk;
          mOut[ob] = (float)mN;
        }
        const unsigned long long bal = __ballot(h1 && spk);
        newM1 = (tid & 32) ? (unsigned)(bal >> 32) : (unsigned)(bal & 0xffffffffULL);
        if (h1) {
          if (o == 0) spM[i*40 + n1] = newM1;
          unsigned diff = newM1 ^ oldM;
          double pv = prj[n1*PSZ + o];
          while (diff) {
            unsigned d = diff;
            const int cA = __ffs(d)-1; d &= d-1;
            const bool hB = d!=0; const int cB = hB ? __ffs(d)-1 : cA; d &= d-1;
            const bool hC = d!=0; const int cC = hC ? __ffs(d)-1 : cA; d &= d-1;
            const bool hD = d!=0; const int cD = hD ? __ffs(d)-1 : cA; d &= d-1;
            diff = d;
            const double wA = (double)aggT[(i*PSZ+cA)*PSZ+o];
            const double wB = (double)aggT[(i*PSZ+cB)*PSZ+o];
            const double wC = (double)aggT[(i*PSZ+cC)*PSZ+o];
            const double wD = (double)aggT[(i*PSZ+cD)*PSZ+o];
            pv += ((newM1>>cA)&1u) ? wA : -wA;
            pv += hB ? (((newM1>>cB)&1u) ? wB : -wB) : 0.0;
            pv += hC ? (((newM1>>cC)&1u) ? wC : -wC) : 0.0;
            pv += hD ? (((newM1>>cD)&1u) ? wD : -wD) : 0.0;
          }
          prw[n1*PSZ + o] = pv;
        }
      }

      // ---- scatter source-i spikes into acc regs (loads drain lazily, next steps)
      const unsigned g0 = newM0, g1 = h1 ? newM1 : 0u;
      if      (i == 0) scatJ<0>(g0, g1, n0, n1v, gw, o, acc0, acc1);
      else if (i == 1) scatJ<1>(g0, g1, n0, n1v, gw, o, acc0, acc1);
      else if (i == 2) scatJ<2>(g0, g1, n0, n1v, gw, o, acc0, acc1);
      else if (i == 3) scatJ<3>(g0, g1, n0, n1v, gw, o, acc0, acc1);
      else if (i == 4) scatJ<4>(g0, g1, n0, n1v, gw, o, acc0, acc1);
      else if (i == 5) scatJ<5>(g0, g1, n0, n1v, gw, o, acc0, acc1);
      else if (i == 6) scatJ<6>(g0, g1, n0, n1v, gw, o, acc0, acc1);
      else             scatJ<7>(g0, g1, n0, n1v, gw, o, acc0, acc1);

      STEP_BAR();      // lgkmcnt(0) + s_barrier only; vmem stays in flight
      rb ^= 1;
    }
  }

  // persist chunk state (64 steps -> rb back to 0)
  #pragma unroll
  for (int i = 0; i < NPOPS; ++i) {
    const size_t eA = mbase + i*NEUR + n0*PSZ + o;
    memG[eA] = mem0[i]; bbrG[eA] = bbr0[i]; accG[eA] = acc0[i];
    if (h1) {
      const size_t eB = mbase + i*NEUR + n1*PSZ + o;
      memG[eB] = mem1[i]; bbrG[eB] = bbr1[i]; accG[eB] = acc1[i];
    }
  }
  for (int e = tid; e < NEUR; e += 640) stProj[b*NEUR + e] = proj[0][e];
  for (int e = tid; e < NPOPS*NBAR; e += 640) stSp[b*NPOPS*NBAR + e] = spM[(e/NBAR)*40 + (e%NBAR)];
}

// ---------------- readout ----------------
__global__ __launch_bounds__(256) void kread(const float* __restrict__ hBase,
    const float* __restrict__ ro_w, const float* __restrict__ ro_b, float* __restrict__ outp)
{
  __shared__ double part[2][128];
  __shared__ double meanv[128];
  __shared__ double lg[36];
  const int b = blockIdx.x, tid = threadIdx.x;
  const int d = tid & 127, half = tid >> 7;
  double acc = 0.0;
  for (int r = half*1248; r < half*1248 + 1248; ++r)
    acc += (double)hBase[((size_t)b*2496 + r)*256 + 128 + d];
  part[half][d] = acc;
  __syncthreads();
  if (tid < 128) meanv[tid] = (part[0][tid] + part[1][tid]) / 2496.0;
  __syncthreads();
  if (tid < 36) {
    double a = (double)ro_b[tid];
    for (int e = 0; e < 128; ++e) a += meanv[e]*(double)ro_w[tid*128 + e];
    lg[tid] = a;
  }
  __syncthreads();
  if (tid == 0) {
    double mx = lg[0];
    for (int dd = 1; dd < 36; ++dd) mx = fmax(mx, lg[dd]);
    double ex[36]; double sum = 0.0;
    for (int dd = 0; dd < 36; ++dd) { ex[dd] = exp(lg[dd]-mx); sum += ex[dd]; }
    for (int dd = 0; dd < 36; ++dd) outp[b*36 + dd] = (float)(ex[dd]/sum);
  }
}

// ---------------- launcher ----------------
extern "C" void kernel_launch(void* const* d_in, const int* in_sizes, int n_in,
                              void* d_out, int out_size, void* d_ws, size_t ws_size,
                              hipStream_t stream)
{
  const float* inp     = (const float*)d_in[0];
  const float* comp_w  = (const float*)d_in[1];
  const float* comp_b  = (const float*)d_in[2];
  const float* th_w    = (const float*)d_in[3];
  const float* th_b    = (const float*)d_in[4];
  const float* pop_w   = (const float*)d_in[5];
  const float* pop_b   = (const float*)d_in[6];
  const float* tau_adp = (const float*)d_in[7];
  const float* tau_m   = (const float*)d_in[8];
  const float* agg_w   = (const float*)d_in[9];
  const float* agg_b   = (const float*)d_in[10];
  const float* ro_w    = (const float*)d_in[11];
  const float* ro_b    = (const float*)d_in[12];

  char* ws = (char*)d_ws;
  double*   xt     = (double*)  (ws + OFS_XT);
  double*   drive  = (double*)  (ws + OFS_DRIVE);
  int*      idxg   = (int*)     (ws + OFS_IDX);
  float*    gw     = (float*)   (ws + OFS_GW);
  float*    aggT   = (float*)   (ws + OFS_AGGT);
  double*   cbias  = (double*)  (ws + OFS_CBIAS);
  double*   alro   = (double*)  (ws + OFS_ALRO);
  double*   memG   = (double*)  (ws + OFS_MEMG);
  double*   bbrG   = (double*)  (ws + OFS_BBRG);
  double*   accG   = (double*)  (ws + OFS_ACCG);
  double*   stProj = (double*)  (ws + OFS_STPROJ);
  unsigned* stSp   = (unsigned*)(ws + OFS_STSP);

  float* outp = (float*)d_out;                 // (64,36) softmax
  float* hOut = outp + 64*36;                  // (64,64,39,256)
  float* mOut = hOut + 64*64*39*256;           // (64,64,39,256)

  kconv <<<BATCH*NBAR, 256, 0, stream>>>(inp, comp_w, comp_b, xt);
  kprepw<<<NPOPS*NBAR, 256, 0, stream>>>(pop_w, gw);
  kprepn<<<39, 256, 0, stream>>>(th_b, pop_b, tau_adp, tau_m, agg_w, cbias, alro, aggT);
  ksim  <<<TSTEPS*BATCH, 128, 0, stream>>>(xt, idxg);
  for (int c0 = 0; c0 < TSTEPS; c0 += TCH) {
    kdrive<<<NBAR*8, 512, 0, stream>>>(xt, th_w, cbias, drive, c0);
    krec  <<<BATCH, 640, 0, stream>>>(drive, idxg, gw, aggT, agg_b, alro,
                                      memG, bbrG, accG, stProj, stSp, hOut, mOut, c0);
  }
  kread <<<BATCH, 256, 0, stream>>>(hOut, ro_w, ro_b, outp);
}